// Round 5
// baseline (2414.632 us; speedup 1.0000x reference)
//
#include <hip/hip_runtime.h>

// ---------------------------------------------------------------------------
// GATv2 3-layer GNN encoder. N=50000 nodes, E=800000 edges, dims 128.
// CSR build + degree-sort (once) -> per layer: [dual gemm (xl,xr),
// fused edge-score + segment-softmax + aggregate + bias + LN + ReLU].
// fused: ONE 64-lane wave per node, thread owns dims {lane, lane+64};
// no barriers in edge loop; edge idx batch-loaded, extracted via readlane.
// ---------------------------------------------------------------------------

__global__ __launch_bounds__(256) void hist_kernel(const int* __restrict__ dst,
                                                   int* __restrict__ deg, int nE) {
  int i = blockIdx.x * 256 + threadIdx.x;
  if (i < nE) atomicAdd(&deg[dst[i]], 1);
}

// 1024-thread block, shuffle-based inclusive scan, 3 barriers/iter.
__global__ __launch_bounds__(1024) void scan_kernel(const int* __restrict__ deg,
                                                    int* __restrict__ rowptr, int n) {
  __shared__ int wsum[16];
  __shared__ int wbase[16];
  int tid = threadIdx.x, wid = tid >> 6, lane = tid & 63;
  if (tid == 0) rowptr[0] = 0;
  int carry = 0;
  for (int base = 0; base < n; base += 1024) {
    int i = base + tid;
    int v = (i < n) ? deg[i] : 0;
#pragma unroll
    for (int o = 1; o < 64; o <<= 1) {  // in-wave inclusive scan
      int t = __shfl_up(v, o);
      if (lane >= o) v += t;
    }
    if (lane == 63) wsum[wid] = v;
    __syncthreads();
    if (wid == 0 && lane < 16) {
      int s = wsum[lane];
#pragma unroll
      for (int o = 1; o < 16; o <<= 1) {
        int t = __shfl_up(s, o);
        if (lane >= o) s += t;
      }
      wbase[lane] = s;  // inclusive wave-sum scan
    }
    __syncthreads();
    int myb = (wid > 0) ? wbase[wid - 1] : 0;
    int tot = wbase[15];
    if (i < n) rowptr[i + 1] = carry + myb + v;
    carry += tot;
    __syncthreads();  // protect wsum/wbase for next iter
  }
}

__global__ __launch_bounds__(256) void scatter_kernel(const int* __restrict__ dst,
                                                      const int* __restrict__ rowptr,
                                                      int* __restrict__ cnt,
                                                      int* __restrict__ eperm, int nE) {
  int i = blockIdx.x * 256 + threadIdx.x;
  if (i < nE) {
    int d = dst[i];
    int p = atomicAdd(&cnt[d], 1);
    eperm[rowptr[d] + p] = i;
  }
}

// --- degree sort: nodeorder = nodes sorted by degree descending (bucketed) ---
__global__ __launch_bounds__(256) void deg_hist(const int* __restrict__ rowptr,
                                                int* __restrict__ dh, int nN) {
  int i = blockIdx.x * 256 + threadIdx.x;
  if (i < nN) {
    int dg = min(rowptr[i + 1] - rowptr[i], 255);
    atomicAdd(&dh[dg], 1);
  }
}

__global__ __launch_bounds__(256) void deg_scan(const int* __restrict__ dh,
                                                int* __restrict__ dbase) {
  __shared__ int s[256];
  int t = threadIdx.x;
  s[t] = dh[t];
  __syncthreads();
  for (int ofs = 1; ofs < 256; ofs <<= 1) {
    int v = (t >= ofs) ? s[t - ofs] : 0;
    __syncthreads();
    s[t] += v;
    __syncthreads();
  }
  dbase[t] = s[255] - s[t];  // descending-degree exclusive bases
}

__global__ __launch_bounds__(256) void deg_scatter(const int* __restrict__ rowptr,
                                                   const int* __restrict__ dbase,
                                                   int* __restrict__ dcnt,
                                                   int* __restrict__ nodeorder, int nN) {
  int i = blockIdx.x * 256 + threadIdx.x;
  if (i < nN) {
    int dg = min(rowptr[i + 1] - rowptr[i], 255);
    int p = atomicAdd(&dcnt[dg], 1);
    nodeorder[dbase[dg] + p] = i;
  }
}

// Y1 = X@W1+b1, Y2 = X@W2+b2 in one pass (X tile staged once).
// X: nrows x 128, W: 128 x 128. Thread t: col = t&127, owns 32 rows (half rh).
__global__ __launch_bounds__(256) void node_gemm_dual(const float* __restrict__ X,
                                                      const float* __restrict__ W1,
                                                      const float* __restrict__ b1,
                                                      const float* __restrict__ W2,
                                                      const float* __restrict__ b2,
                                                      float* __restrict__ Y1,
                                                      float* __restrict__ Y2, int nrows) {
  __shared__ float Xs[64][36];
  __shared__ float Ws1[32][128];
  __shared__ float Ws2[32][128];
  int tid = threadIdx.x;
  int r0 = blockIdx.x * 64;
  int col = tid & 127;
  int rh = tid >> 7;
  float acc1[32], acc2[32];
#pragma unroll
  for (int i = 0; i < 32; ++i) acc1[i] = acc2[i] = 0.f;

  for (int k0 = 0; k0 < 128; k0 += 32) {
    __syncthreads();
#pragma unroll
    for (int j = tid; j < 512; j += 256) {
      int r = j >> 3, kk = (j & 7) << 2;
      float4 v = make_float4(0.f, 0.f, 0.f, 0.f);
      if (r0 + r < nrows) v = *(const float4*)&X[(size_t)(r0 + r) * 128 + k0 + kk];
      *(float4*)&Xs[r][kk] = v;
    }
#pragma unroll
    for (int j = tid; j < 1024; j += 256) {
      int k = j >> 5, nn = (j & 31) << 2;
      *(float4*)&Ws1[k][nn] = *(const float4*)&W1[(size_t)(k0 + k) * 128 + nn];
      *(float4*)&Ws2[k][nn] = *(const float4*)&W2[(size_t)(k0 + k) * 128 + nn];
    }
    __syncthreads();
#pragma unroll
    for (int k4 = 0; k4 < 32; k4 += 4) {
      float u0 = Ws1[k4][col], u1 = Ws1[k4 + 1][col];
      float u2 = Ws1[k4 + 2][col], u3 = Ws1[k4 + 3][col];
      float v0 = Ws2[k4][col], v1 = Ws2[k4 + 1][col];
      float v2 = Ws2[k4 + 2][col], v3 = Ws2[k4 + 3][col];
#pragma unroll
      for (int r = 0; r < 32; ++r) {
        float4 xv = *(const float4*)&Xs[rh * 32 + r][k4];  // broadcast read
        acc1[r] += xv.x * u0 + xv.y * u1 + xv.z * u2 + xv.w * u3;
        acc2[r] += xv.x * v0 + xv.y * v1 + xv.z * v2 + xv.w * v3;
      }
    }
  }
  float bb1 = b1[col], bb2 = b2[col];
#pragma unroll
  for (int r = 0; r < 32; ++r) {
    int row = r0 + rh * 32 + r;
    if (row < nrows) {
      Y1[(size_t)row * 128 + col] = acc1[r] + bb1;
      Y2[(size_t)row * 128 + col] = acc2[r] + bb2;
    }
  }
}

// Fused GATv2 layer. ONE 64-lane wave per node (4 nodes / 256-thread block).
// Thread owns dims cL=lane, cH=lane+64. H=4: head = c>>5 -> pL reduces over
// its 32-lane group to head(cL), pH to head(cH); per-thread denominators are
// group-uniform. H=1: p = pL+pH, full 64-lane butterfly. No LDS, no barriers.
template <int H>
__global__ __launch_bounds__(256) void fused_gat(const float* __restrict__ xl,
                                                 const float* __restrict__ xr,
                                                 const float* __restrict__ ea,
                                                 const float* __restrict__ We,
                                                 const float* __restrict__ att,
                                                 const int* __restrict__ rowptr,
                                                 const int* __restrict__ eperm,
                                                 const int* __restrict__ src,
                                                 const int* __restrict__ nodeorder,
                                                 const float* __restrict__ bias,
                                                 const float* __restrict__ gam,
                                                 const float* __restrict__ bet,
                                                 float* __restrict__ out, int nN) {
  const int wid = threadIdx.x >> 6;
  const int lane = threadIdx.x & 63;
  const int bn = blockIdx.x * 4 + wid;
  if (bn >= nN) return;
  const int n = __builtin_amdgcn_readfirstlane(nodeorder[bn]);
  const int rb = __builtin_amdgcn_readfirstlane(rowptr[n]);
  const int re = __builtin_amdgcn_readfirstlane(rowptr[n + 1]);
  const int cL = lane, cH = lane + 64;

  float WcL[32], WcH[32];
#pragma unroll
  for (int k = 0; k < 32; ++k) {
    WcL[k] = We[k * 128 + cL];
    WcH[k] = We[k * 128 + cH];
  }
  const float attL = att[cL], attH = att[cH];
  const float xrL = xr[(size_t)n * 128 + cL];
  const float xrH = xr[(size_t)n * 128 + cH];

  float dL = 0.f, dH = 0.f, accL = 0.f, accH = 0.f;

  for (int b0 = rb; b0 < re; b0 += 64) {
    const int cnt = min(64, re - b0);
    const int jj = b0 + lane;
    const int ev = (jj < re) ? eperm[jj] : 0;  // one coalesced load / 64 edges
    const int sv = (jj < re) ? src[ev] : 0;    // one gather / 64 edges

    for (int i = 0; i < cnt; i += 2) {
      const int i0 = i, i1 = min(i + 1, cnt - 1);
      const int e0 = __builtin_amdgcn_readlane(ev, i0);
      const int e1 = __builtin_amdgcn_readlane(ev, i1);
      const int s0 = __builtin_amdgcn_readlane(sv, i0);
      const int s1 = __builtin_amdgcn_readlane(sv, i1);

      const float g0L = xl[(size_t)s0 * 128 + cL];  // 256B coalesced gathers
      const float g0H = xl[(size_t)s0 * 128 + cH];
      const float g1L = xl[(size_t)s1 * 128 + cL];
      const float g1H = xl[(size_t)s1 * 128 + cH];
      const float* r0p = ea + (size_t)e0 * 32;  // uniform -> s_load
      const float* r1p = ea + (size_t)e1 * 32;

      float m0L = g0L + xrL, m0H = g0H + xrH;
      float m1L = g1L + xrL, m1H = g1H + xrH;
#pragma unroll
      for (int k = 0; k < 32; k += 4) {
        float4 q0 = *(const float4*)(r0p + k);
        float4 q1 = *(const float4*)(r1p + k);
        m0L += q0.x * WcL[k] + q0.y * WcL[k + 1] + q0.z * WcL[k + 2] + q0.w * WcL[k + 3];
        m0H += q0.x * WcH[k] + q0.y * WcH[k + 1] + q0.z * WcH[k + 2] + q0.w * WcH[k + 3];
        m1L += q1.x * WcL[k] + q1.y * WcL[k + 1] + q1.z * WcL[k + 2] + q1.w * WcL[k + 3];
        m1H += q1.x * WcH[k] + q1.y * WcH[k + 1] + q1.z * WcH[k + 2] + q1.w * WcH[k + 3];
      }
      float p0L = fmaxf(m0L, 0.2f * m0L) * attL;
      float p0H = fmaxf(m0H, 0.2f * m0H) * attH;
      float p1L = fmaxf(m1L, 0.2f * m1L) * attL;
      float p1H = fmaxf(m1H, 0.2f * m1H) * attH;

      if (H == 4) {
#pragma unroll
        for (int o = 16; o >= 1; o >>= 1) {  // 32-lane group == head
          p0L += __shfl_xor(p0L, o);
          p0H += __shfl_xor(p0H, o);
          p1L += __shfl_xor(p1L, o);
          p1H += __shfl_xor(p1H, o);
        }
      } else {
        float p0 = p0L + p0H, p1 = p1L + p1H;
#pragma unroll
        for (int o = 32; o >= 1; o >>= 1) {
          p0 += __shfl_xor(p0, o);
          p1 += __shfl_xor(p1, o);
        }
        p0L = p0H = p0;
        p1L = p1H = p1;
      }

      float w0L = __expf(fminf(p0L, 80.f));
      float w0H = __expf(fminf(p0H, 80.f));
      float w1L = __expf(fminf(p1L, 80.f));
      float w1H = __expf(fminf(p1H, 80.f));
      if (i1 == i0) w1L = w1H = 0.f;  // masked padding (uniform)
      dL += w0L + w1L;
      dH += w0H + w1H;
      accL += w0L * g0L + w1L * g1L;
      accH += w0H * g0H + w1H * g1H;
    }
  }

  const float rdL = (dL > 0.f) ? 1.f / dL : 0.f;
  const float rdH = (dH > 0.f) ? 1.f / dH : 0.f;
  float y0 = accL * rdL + bias[cL];
  float y1 = accH * rdH + bias[cH];

  // LayerNorm over 128 dims: full in-wave butterfly (2 dims/thread)
  float sm = y0 + y1, sq = y0 * y0 + y1 * y1;
#pragma unroll
  for (int o = 32; o >= 1; o >>= 1) {
    sm += __shfl_xor(sm, o);
    sq += __shfl_xor(sq, o);
  }
  const float mu = sm * (1.f / 128.f);
  const float var = sq * (1.f / 128.f) - mu * mu;
  const float rstd = rsqrtf(var + 1e-5f);
  const float o0 = (y0 - mu) * rstd * gam[cL] + bet[cL];
  const float o1 = (y1 - mu) * rstd * gam[cH] + bet[cH];
  out[(size_t)n * 128 + cL] = fmaxf(o0, 0.f);
  out[(size_t)n * 128 + cH] = fmaxf(o1, 0.f);
}

extern "C" void kernel_launch(void* const* d_in, const int* in_sizes, int n_in,
                              void* d_out, int out_size, void* d_ws, size_t ws_size,
                              hipStream_t stream) {
  const float* x = (const float*)d_in[0];
  const float* ea = (const float*)d_in[1];
  const int* src = (const int*)d_in[2];
  const int* dst = (const int*)d_in[3];
  const int N = in_sizes[0] / 128;
  const int E = in_sizes[2];

  char* w = (char*)d_ws;
  auto alloc = [&](size_t bytes) {
    char* p = w;
    w += (bytes + 255) & ~(size_t)255;
    return p;
  };
  float* xl = (float*)alloc((size_t)N * 128 * 4);
  float* xr = (float*)alloc((size_t)N * 128 * 4);
  float* hA = (float*)alloc((size_t)N * 128 * 4);
  float* hB = (float*)alloc((size_t)N * 128 * 4);
  int* eperm = (int*)alloc((size_t)E * 4);
  int* rowptr = (int*)alloc((size_t)(N + 1) * 4);
  int* deg = (int*)alloc((size_t)N * 4);
  int* cnt = (int*)alloc((size_t)N * 4);
  int* nodeorder = (int*)alloc((size_t)N * 4);
  int* dh = (int*)alloc(256 * 4);
  int* dbase = (int*)alloc(256 * 4);
  int* dcnt = (int*)alloc(256 * 4);

  // CSR by dst + degree-descending node order (src/dst constant across layers)
  hipMemsetAsync(deg, 0, (size_t)N * 4, stream);
  hipMemsetAsync(cnt, 0, (size_t)N * 4, stream);
  hipMemsetAsync(dh, 0, 256 * 4, stream);
  hipMemsetAsync(dcnt, 0, 256 * 4, stream);
  hist_kernel<<<(E + 255) / 256, 256, 0, stream>>>(dst, deg, E);
  scan_kernel<<<1, 1024, 0, stream>>>(deg, rowptr, N);
  scatter_kernel<<<(E + 255) / 256, 256, 0, stream>>>(dst, rowptr, cnt, eperm, E);
  deg_hist<<<(N + 255) / 256, 256, 0, stream>>>(rowptr, dh, N);
  deg_scan<<<1, 256, 0, stream>>>(dh, dbase);
  deg_scatter<<<(N + 255) / 256, 256, 0, stream>>>(rowptr, dbase, dcnt, nodeorder, N);

  for (int l = 0; l < 3; ++l) {
    int bi = 4 + 9 * l;
    const float* Wl = (const float*)d_in[bi + 0];
    const float* bl = (const float*)d_in[bi + 1];
    const float* Wr = (const float*)d_in[bi + 2];
    const float* br = (const float*)d_in[bi + 3];
    const float* We = (const float*)d_in[bi + 4];
    const float* att = (const float*)d_in[bi + 5];
    const float* bo = (const float*)d_in[bi + 6];
    const float* gg = (const float*)d_in[bi + 7];
    const float* be = (const float*)d_in[bi + 8];
    const float* Xin = (l == 0) ? x : ((l == 1) ? hA : hB);
    float* Xout = (l == 2) ? (float*)d_out : ((l == 0) ? hA : hB);

    int gemmGrid = (N + 63) / 64;
    node_gemm_dual<<<gemmGrid, 256, 0, stream>>>(Xin, Wl, bl, Wr, br, xl, xr, N);
    int nGrid = (N + 3) / 4;
    if (l < 2) {
      fused_gat<4><<<nGrid, 256, 0, stream>>>(xl, xr, ea, We, att, rowptr, eperm, src,
                                              nodeorder, bo, gg, be, Xout, N);
    } else {
      fused_gat<1><<<nGrid, 256, 0, stream>>>(xl, xr, ea, We, att, rowptr, eperm, src,
                                              nodeorder, bo, gg, be, Xout, N);
    }
  }
}

// Round 6
// 1049.158 us; speedup vs baseline: 2.3015x; 2.3015x over previous
//
#include <hip/hip_runtime.h>

// ---------------------------------------------------------------------------
// GATv2 3-layer GNN encoder. N=50000 nodes, E=800000 edges, dims 128.
// CSR build + degree-sort (once); per layer: [prep_w (W->W^T bf16),
// MFMA dual GEMM (xl,xr in fp32 from bf16 X), fused edge-score +
// segment-softmax + aggregate + bias + LN + ReLU (writes bf16 X for next
// layer, fp32 d_out on the last)].
// ---------------------------------------------------------------------------

typedef __attribute__((ext_vector_type(8))) short bf16x8;
typedef __attribute__((ext_vector_type(4))) float f32x4;

__device__ inline ushort f2bf(float f) {
  unsigned u = __float_as_uint(f);
  u += 0x7FFF + ((u >> 16) & 1);  // round-to-nearest-even
  return (ushort)(u >> 16);
}

// ---------------- CSR build ----------------

__global__ __launch_bounds__(256) void hist_kernel(const int* __restrict__ dst,
                                                   int* __restrict__ deg, int nE) {
  int i = blockIdx.x * 256 + threadIdx.x;
  if (i < nE) atomicAdd(&deg[dst[i]], 1);
}

__global__ __launch_bounds__(1024) void scan_kernel(const int* __restrict__ deg,
                                                    int* __restrict__ rowptr, int n) {
  __shared__ int wsum[16];
  __shared__ int wbase[16];
  int tid = threadIdx.x, wid = tid >> 6, lane = tid & 63;
  if (tid == 0) rowptr[0] = 0;
  int carry = 0;
  for (int base = 0; base < n; base += 1024) {
    int i = base + tid;
    int v = (i < n) ? deg[i] : 0;
#pragma unroll
    for (int o = 1; o < 64; o <<= 1) {
      int t = __shfl_up(v, o);
      if (lane >= o) v += t;
    }
    if (lane == 63) wsum[wid] = v;
    __syncthreads();
    if (wid == 0 && lane < 16) {
      int s = wsum[lane];
#pragma unroll
      for (int o = 1; o < 16; o <<= 1) {
        int t = __shfl_up(s, o);
        if (lane >= o) s += t;
      }
      wbase[lane] = s;
    }
    __syncthreads();
    int myb = (wid > 0) ? wbase[wid - 1] : 0;
    int tot = wbase[15];
    if (i < n) rowptr[i + 1] = carry + myb + v;
    carry += tot;
    __syncthreads();
  }
}

__global__ __launch_bounds__(256) void scatter_kernel(const int* __restrict__ dst,
                                                      const int* __restrict__ rowptr,
                                                      int* __restrict__ cnt,
                                                      int* __restrict__ eperm, int nE) {
  int i = blockIdx.x * 256 + threadIdx.x;
  if (i < nE) {
    int d = dst[i];
    int p = atomicAdd(&cnt[d], 1);
    eperm[rowptr[d] + p] = i;
  }
}

__global__ __launch_bounds__(256) void deg_hist(const int* __restrict__ rowptr,
                                                int* __restrict__ dh, int nN) {
  int i = blockIdx.x * 256 + threadIdx.x;
  if (i < nN) {
    int dg = min(rowptr[i + 1] - rowptr[i], 255);
    atomicAdd(&dh[dg], 1);
  }
}

__global__ __launch_bounds__(256) void deg_scan(const int* __restrict__ dh,
                                                int* __restrict__ dbase) {
  __shared__ int s[256];
  int t = threadIdx.x;
  s[t] = dh[t];
  __syncthreads();
  for (int ofs = 1; ofs < 256; ofs <<= 1) {
    int v = (t >= ofs) ? s[t - ofs] : 0;
    __syncthreads();
    s[t] += v;
    __syncthreads();
  }
  dbase[t] = s[255] - s[t];
}

__global__ __launch_bounds__(256) void deg_scatter(const int* __restrict__ rowptr,
                                                   const int* __restrict__ dbase,
                                                   int* __restrict__ dcnt,
                                                   int* __restrict__ nodeorder, int nN) {
  int i = blockIdx.x * 256 + threadIdx.x;
  if (i < nN) {
    int dg = min(rowptr[i + 1] - rowptr[i], 255);
    int p = atomicAdd(&dcnt[dg], 1);
    nodeorder[dbase[dg] + p] = i;
  }
}

// ---------------- bf16 prep ----------------

__global__ __launch_bounds__(256) void convert_x(const float* __restrict__ x,
                                                 ushort* __restrict__ xb, int n8) {
  int i = blockIdx.x * 256 + threadIdx.x;
  if (i < n8) {
    float4 a = ((const float4*)x)[i * 2];
    float4 b = ((const float4*)x)[i * 2 + 1];
    union { ushort r[8]; uint4 v; } u;
    u.r[0] = f2bf(a.x); u.r[1] = f2bf(a.y); u.r[2] = f2bf(a.z); u.r[3] = f2bf(a.w);
    u.r[4] = f2bf(b.x); u.r[5] = f2bf(b.y); u.r[6] = f2bf(b.z); u.r[7] = f2bf(b.w);
    ((uint4*)xb)[i] = u.v;
  }
}

// wt[n][k] = bf16(W[k][n]) for both weight matrices. grid 128 x 256.
__global__ __launch_bounds__(256) void prep_w(const float* __restrict__ Wl,
                                              const float* __restrict__ Wr,
                                              ushort* __restrict__ wt1,
                                              ushort* __restrict__ wt2) {
  int idx = blockIdx.x * 256 + threadIdx.x;
  int mat = idx >> 14, rem = idx & 16383;
  int n = rem >> 7, k = rem & 127;
  const float* W = mat ? Wr : Wl;
  ushort* wt = mat ? wt2 : wt1;
  wt[n * 128 + k] = f2bf(W[(size_t)k * 128 + n]);
}

// ---------------- MFMA dual GEMM ----------------
// Y1 = X@W1+b1, Y2 = X@W2+b2. X bf16 [nrows][128], wt = W^T bf16 [128n][128k].
// Block 512 thr = 8 waves; tile 128 rows x 128 cols x K=128 (full).
// Wave (wid): rows RB=(wid&3)*32..+32, cols CB=(wid>>2)*64..+64.
// Frag layout (16x16x32 bf16): A/B lane l elem j: m/n = l&15,
//   k = 4*(l>>4) + (j&3) + 16*(j>>2)  [two 16x16x16 K-halves].
// D lane l reg r: col = l&15, row = 4*(l>>4) + r.
#define XPAD 136  // row stride (elems): 272B = 16B-aligned, banks spread

__device__ inline bf16x8 load_frag(const ushort* p) {
  union { bf16x8 v; unsigned long long q[2]; } u;
  u.q[0] = *(const unsigned long long*)p;         // k+0..3
  u.q[1] = *(const unsigned long long*)(p + 16);  // k+16..19
  return u.v;
}

__global__ __launch_bounds__(512) void gemm_mfma_dual(
    const ushort* __restrict__ xb, const ushort* __restrict__ wt1,
    const ushort* __restrict__ wt2, const float* __restrict__ b1,
    const float* __restrict__ b2, float* __restrict__ y1, float* __restrict__ y2,
    int nrows) {
  __shared__ ushort Xs[128 * XPAD];
  __shared__ ushort W1s[128 * XPAD];
  __shared__ ushort W2s[128 * XPAD];
  const int tid = threadIdx.x;
  const int r0 = blockIdx.x * 128;

#pragma unroll
  for (int i = 0; i < 4; ++i) {  // 2048 16B-chunks per matrix
    int c = tid + i * 512;
    int row = c >> 4, kc = (c & 15) << 3;
    int gr = min(r0 + row, nrows - 1);
    *(uint4*)&Xs[row * XPAD + kc] = *(const uint4*)&xb[(size_t)gr * 128 + kc];
    *(uint4*)&W1s[row * XPAD + kc] = *(const uint4*)&wt1[row * 128 + kc];
    *(uint4*)&W2s[row * XPAD + kc] = *(const uint4*)&wt2[row * 128 + kc];
  }
  __syncthreads();

  const int wid = tid >> 6, lane = tid & 63;
  const int lr = lane & 15, lg = lane >> 4;
  const int RB = (wid & 3) * 32, CB = (wid >> 2) * 64;

  f32x4 acc1[2][4] = {{{0.f}}};
  f32x4 acc2[2][4] = {{{0.f}}};

#pragma unroll
  for (int ks = 0; ks < 4; ++ks) {
    const int kb = ks * 32 + lg * 4;
    bf16x8 a0 = load_frag(&Xs[(RB + lr) * XPAD + kb]);
    bf16x8 a1 = load_frag(&Xs[(RB + 16 + lr) * XPAD + kb]);
#pragma unroll
    for (int nt = 0; nt < 4; ++nt) {
      const int n = CB + nt * 16 + lr;
      bf16x8 bf1 = load_frag(&W1s[n * XPAD + kb]);
      acc1[0][nt] = __builtin_amdgcn_mfma_f32_16x16x32_bf16(a0, bf1, acc1[0][nt], 0, 0, 0);
      acc1[1][nt] = __builtin_amdgcn_mfma_f32_16x16x32_bf16(a1, bf1, acc1[1][nt], 0, 0, 0);
      bf16x8 bf2 = load_frag(&W2s[n * XPAD + kb]);
      acc2[0][nt] = __builtin_amdgcn_mfma_f32_16x16x32_bf16(a0, bf2, acc2[0][nt], 0, 0, 0);
      acc2[1][nt] = __builtin_amdgcn_mfma_f32_16x16x32_bf16(a1, bf2, acc2[1][nt], 0, 0, 0);
    }
  }

#pragma unroll
  for (int nt = 0; nt < 4; ++nt) {
    const int col = CB + nt * 16 + lr;
    const float bb1 = b1[col], bb2 = b2[col];
#pragma unroll
    for (int mt = 0; mt < 2; ++mt) {
#pragma unroll
      for (int r = 0; r < 4; ++r) {
        int gr = r0 + RB + mt * 16 + lg * 4 + r;
        if (gr < nrows) {
          y1[(size_t)gr * 128 + col] = acc1[mt][nt][r] + bb1;
          y2[(size_t)gr * 128 + col] = acc2[mt][nt][r] + bb2;
        }
      }
    }
  }
}

// ---------------- fused GATv2 layer ----------------
// ONE 64-lane wave per node (4 nodes / 256-thread block). Thread owns dims
// cL=lane, cH=lane+64. H=4: head = c>>5, 32-lane-group butterfly reduce.
// H=1: full 64-lane butterfly. No LDS, no barriers. OB: write bf16 (next
// layer's GEMM input) instead of fp32.
template <int H, bool OB>
__global__ __launch_bounds__(256) void fused_gat(const float* __restrict__ xl,
                                                 const float* __restrict__ xr,
                                                 const float* __restrict__ ea,
                                                 const float* __restrict__ We,
                                                 const float* __restrict__ att,
                                                 const int* __restrict__ rowptr,
                                                 const int* __restrict__ eperm,
                                                 const int* __restrict__ src,
                                                 const int* __restrict__ nodeorder,
                                                 const float* __restrict__ bias,
                                                 const float* __restrict__ gam,
                                                 const float* __restrict__ bet,
                                                 float* __restrict__ out,
                                                 ushort* __restrict__ outb, int nN) {
  const int wid = threadIdx.x >> 6;
  const int lane = threadIdx.x & 63;
  const int bn = blockIdx.x * 4 + wid;
  if (bn >= nN) return;
  const int n = __builtin_amdgcn_readfirstlane(nodeorder[bn]);
  const int rb = __builtin_amdgcn_readfirstlane(rowptr[n]);
  const int re = __builtin_amdgcn_readfirstlane(rowptr[n + 1]);
  const int cL = lane, cH = lane + 64;

  float WcL[32], WcH[32];
#pragma unroll
  for (int k = 0; k < 32; ++k) {
    WcL[k] = We[k * 128 + cL];
    WcH[k] = We[k * 128 + cH];
  }
  const float attL = att[cL], attH = att[cH];
  const float xrL = xr[(size_t)n * 128 + cL];
  const float xrH = xr[(size_t)n * 128 + cH];

  float dL = 0.f, dH = 0.f, accL = 0.f, accH = 0.f;

  for (int b0 = rb; b0 < re; b0 += 64) {
    const int cnt = min(64, re - b0);
    const int jj = b0 + lane;
    const int ev = (jj < re) ? eperm[jj] : 0;
    const int sv = (jj < re) ? src[ev] : 0;

    for (int i = 0; i < cnt; i += 2) {
      const int i0 = i, i1 = min(i + 1, cnt - 1);
      const int e0 = __builtin_amdgcn_readlane(ev, i0);
      const int e1 = __builtin_amdgcn_readlane(ev, i1);
      const int s0 = __builtin_amdgcn_readlane(sv, i0);
      const int s1 = __builtin_amdgcn_readlane(sv, i1);

      const float g0L = xl[(size_t)s0 * 128 + cL];
      const float g0H = xl[(size_t)s0 * 128 + cH];
      const float g1L = xl[(size_t)s1 * 128 + cL];
      const float g1H = xl[(size_t)s1 * 128 + cH];
      const float* r0p = ea + (size_t)e0 * 32;
      const float* r1p = ea + (size_t)e1 * 32;

      float m0L = g0L + xrL, m0H = g0H + xrH;
      float m1L = g1L + xrL, m1H = g1H + xrH;
#pragma unroll
      for (int k = 0; k < 32; k += 4) {
        float4 q0 = *(const float4*)(r0p + k);
        float4 q1 = *(const float4*)(r1p + k);
        m0L += q0.x * WcL[k] + q0.y * WcL[k + 1] + q0.z * WcL[k + 2] + q0.w * WcL[k + 3];
        m0H += q0.x * WcH[k] + q0.y * WcH[k + 1] + q0.z * WcH[k + 2] + q0.w * WcH[k + 3];
        m1L += q1.x * WcL[k] + q1.y * WcL[k + 1] + q1.z * WcL[k + 2] + q1.w * WcL[k + 3];
        m1H += q1.x * WcH[k] + q1.y * WcH[k + 1] + q1.z * WcH[k + 2] + q1.w * WcH[k + 3];
      }
      float p0L = fmaxf(m0L, 0.2f * m0L) * attL;
      float p0H = fmaxf(m0H, 0.2f * m0H) * attH;
      float p1L = fmaxf(m1L, 0.2f * m1L) * attL;
      float p1H = fmaxf(m1H, 0.2f * m1H) * attH;

      if (H == 4) {
#pragma unroll
        for (int o = 16; o >= 1; o >>= 1) {
          p0L += __shfl_xor(p0L, o);
          p0H += __shfl_xor(p0H, o);
          p1L += __shfl_xor(p1L, o);
          p1H += __shfl_xor(p1H, o);
        }
      } else {
        float p0 = p0L + p0H, p1 = p1L + p1H;
#pragma unroll
        for (int o = 32; o >= 1; o >>= 1) {
          p0 += __shfl_xor(p0, o);
          p1 += __shfl_xor(p1, o);
        }
        p0L = p0H = p0;
        p1L = p1H = p1;
      }

      float w0L = __expf(fminf(p0L, 80.f));
      float w0H = __expf(fminf(p0H, 80.f));
      float w1L = __expf(fminf(p1L, 80.f));
      float w1H = __expf(fminf(p1H, 80.f));
      if (i1 == i0) w1L = w1H = 0.f;
      dL += w0L + w1L;
      dH += w0H + w1H;
      accL += w0L * g0L + w1L * g1L;
      accH += w0H * g0H + w1H * g1H;
    }
  }

  const float rdL = (dL > 0.f) ? 1.f / dL : 0.f;
  const float rdH = (dH > 0.f) ? 1.f / dH : 0.f;
  float y0 = accL * rdL + bias[cL];
  float y1 = accH * rdH + bias[cH];

  float sm = y0 + y1, sq = y0 * y0 + y1 * y1;
#pragma unroll
  for (int o = 32; o >= 1; o >>= 1) {
    sm += __shfl_xor(sm, o);
    sq += __shfl_xor(sq, o);
  }
  const float mu = sm * (1.f / 128.f);
  const float var = sq * (1.f / 128.f) - mu * mu;
  const float rstd = rsqrtf(var + 1e-5f);
  const float o0 = fmaxf((y0 - mu) * rstd * gam[cL] + bet[cL], 0.f);
  const float o1 = fmaxf((y1 - mu) * rstd * gam[cH] + bet[cH], 0.f);
  if (OB) {
    outb[(size_t)n * 128 + cL] = f2bf(o0);
    outb[(size_t)n * 128 + cH] = f2bf(o1);
  } else {
    out[(size_t)n * 128 + cL] = o0;
    out[(size_t)n * 128 + cH] = o1;
  }
}

extern "C" void kernel_launch(void* const* d_in, const int* in_sizes, int n_in,
                              void* d_out, int out_size, void* d_ws, size_t ws_size,
                              hipStream_t stream) {
  const float* x = (const float*)d_in[0];
  const float* ea = (const float*)d_in[1];
  const int* src = (const int*)d_in[2];
  const int* dst = (const int*)d_in[3];
  const int N = in_sizes[0] / 128;
  const int E = in_sizes[2];

  char* w = (char*)d_ws;
  auto alloc = [&](size_t bytes) {
    char* p = w;
    w += (bytes + 255) & ~(size_t)255;
    return p;
  };
  float* xl = (float*)alloc((size_t)N * 128 * 4);
  float* xr = (float*)alloc((size_t)N * 128 * 4);
  ushort* xb = (ushort*)alloc((size_t)N * 128 * 2);
  ushort* wt1 = (ushort*)alloc(128 * 128 * 2);
  ushort* wt2 = (ushort*)alloc(128 * 128 * 2);
  int* eperm = (int*)alloc((size_t)E * 4);
  int* rowptr = (int*)alloc((size_t)(N + 1) * 4);
  int* deg = (int*)alloc((size_t)N * 4);
  int* cnt = (int*)alloc((size_t)N * 4);
  int* nodeorder = (int*)alloc((size_t)N * 4);
  int* dh = (int*)alloc(256 * 4);
  int* dbase = (int*)alloc(256 * 4);
  int* dcnt = (int*)alloc(256 * 4);

  // CSR by dst + degree-descending node order (src/dst constant across layers)
  hipMemsetAsync(deg, 0, (size_t)N * 4, stream);
  hipMemsetAsync(cnt, 0, (size_t)N * 4, stream);
  hipMemsetAsync(dh, 0, 256 * 4, stream);
  hipMemsetAsync(dcnt, 0, 256 * 4, stream);
  hist_kernel<<<(E + 255) / 256, 256, 0, stream>>>(dst, deg, E);
  scan_kernel<<<1, 1024, 0, stream>>>(deg, rowptr, N);
  scatter_kernel<<<(E + 255) / 256, 256, 0, stream>>>(dst, rowptr, cnt, eperm, E);
  deg_hist<<<(N + 255) / 256, 256, 0, stream>>>(rowptr, dh, N);
  deg_scan<<<1, 256, 0, stream>>>(dh, dbase);
  deg_scatter<<<(N + 255) / 256, 256, 0, stream>>>(rowptr, dbase, dcnt, nodeorder, N);

  int n8 = N * 128 / 8;
  convert_x<<<(n8 + 255) / 256, 256, 0, stream>>>(x, xb, n8);

  for (int l = 0; l < 3; ++l) {
    int bi = 4 + 9 * l;
    const float* Wl = (const float*)d_in[bi + 0];
    const float* bl = (const float*)d_in[bi + 1];
    const float* Wr = (const float*)d_in[bi + 2];
    const float* br = (const float*)d_in[bi + 3];
    const float* We = (const float*)d_in[bi + 4];
    const float* att = (const float*)d_in[bi + 5];
    const float* bo = (const float*)d_in[bi + 6];
    const float* gg = (const float*)d_in[bi + 7];
    const float* be = (const float*)d_in[bi + 8];

    prep_w<<<128, 256, 0, stream>>>(Wl, Wr, wt1, wt2);
    gemm_mfma_dual<<<(N + 127) / 128, 512, 0, stream>>>(xb, wt1, wt2, bl, br, xl, xr, N);
    int nGrid = (N + 3) / 4;
    if (l < 2) {
      fused_gat<4, true><<<nGrid, 256, 0, stream>>>(xl, xr, ea, We, att, rowptr, eperm,
                                                    src, nodeorder, bo, gg, be, nullptr,
                                                    xb, N);
    } else {
      fused_gat<1, false><<<nGrid, 256, 0, stream>>>(xl, xr, ea, We, att, rowptr, eperm,
                                                     src, nodeorder, bo, gg, be,
                                                     (float*)d_out, nullptr, N);
    }
  }
}